// Round 1
// baseline (335.027 us; speedup 1.0000x reference)
//
#include <hip/hip_runtime.h>

using u32 = unsigned int;

// ---- workspace layout (u32 words) ----
#define H1_BINS 4096   // bits [30:19]  (12 bits)
#define H2_BINS 2048   // bits [18:8]   (11 bits)
#define H3_BINS 256    // bits [7:0]    (8 bits)
#define H1_OFF  0
#define H2_OFF  (H1_OFF + 2 * H1_BINS)       // 8192
#define H3_OFF  (H2_OFF + 2 * H2_BINS)       // 12288
#define SEL_OFF (H3_OFF + 2 * H3_BINS)       // 12800
#define SEL_WORDS 8
// sel fields per matrix: 0=p1, 1=p2, 2=G1, 3=t(threshold bits), 4=R, 5=G12, 6=ecnt
#define EQ_OFF  (SEL_OFF + 2 * SEL_WORDS)    // 12816
#define EQ_CAP  4096
#define ZERO_WORDS EQ_OFF                    // zero hists + sel; eqlist needs no init

__device__ __forceinline__ u32 absbits(u32 x) { return x & 0x7FFFFFFFu; }

// ---------- histogram pass 1: bits [30:19] ----------
__global__ void k_hist1(const float* __restrict__ in0, const float* __restrict__ in1,
                        int n0, int n1, u32* __restrict__ ws) {
    __shared__ u32 h[H1_BINS];
    const int m = blockIdx.y;
    const u32* in = (const u32*)(m ? in1 : in0);
    const int n = m ? n1 : n0;
    const int n4 = n >> 2;
    for (int i = threadIdx.x; i < H1_BINS; i += blockDim.x) h[i] = 0;
    __syncthreads();
    const uint4* v = (const uint4*)in;
    const int stride = gridDim.x * blockDim.x;
    for (int i = blockIdx.x * blockDim.x + threadIdx.x; i < n4; i += stride) {
        uint4 x = v[i];
        atomicAdd(&h[absbits(x.x) >> 19], 1u);
        atomicAdd(&h[absbits(x.y) >> 19], 1u);
        atomicAdd(&h[absbits(x.z) >> 19], 1u);
        atomicAdd(&h[absbits(x.w) >> 19], 1u);
    }
    if (blockIdx.x == 0 && (int)threadIdx.x < (n & 3)) {   // tail (unused for 4-divisible n)
        u32 u = absbits(in[n4 * 4 + threadIdx.x]);
        atomicAdd(&h[u >> 19], 1u);
    }
    __syncthreads();
    u32* g = ws + H1_OFF + m * H1_BINS;
    for (int i = threadIdx.x; i < H1_BINS; i += blockDim.x)
        if (h[i]) atomicAdd(&g[i], h[i]);
}

// ---------- histogram pass 2: bits [18:8] among (bits>>19)==p1 ----------
__global__ void k_hist2(const float* __restrict__ in0, const float* __restrict__ in1,
                        int n0, int n1, u32* __restrict__ ws) {
    __shared__ u32 h[H2_BINS];
    const int m = blockIdx.y;
    const u32* in = (const u32*)(m ? in1 : in0);
    const int n = m ? n1 : n0;
    const int n4 = n >> 2;
    const u32 p1 = ws[SEL_OFF + m * SEL_WORDS + 0];
    for (int i = threadIdx.x; i < H2_BINS; i += blockDim.x) h[i] = 0;
    __syncthreads();
    const uint4* v = (const uint4*)in;
    const int stride = gridDim.x * blockDim.x;
    for (int i = blockIdx.x * blockDim.x + threadIdx.x; i < n4; i += stride) {
        uint4 x = v[i];
        u32 a;
        a = absbits(x.x); if ((a >> 19) == p1) atomicAdd(&h[(a >> 8) & 0x7FFu], 1u);
        a = absbits(x.y); if ((a >> 19) == p1) atomicAdd(&h[(a >> 8) & 0x7FFu], 1u);
        a = absbits(x.z); if ((a >> 19) == p1) atomicAdd(&h[(a >> 8) & 0x7FFu], 1u);
        a = absbits(x.w); if ((a >> 19) == p1) atomicAdd(&h[(a >> 8) & 0x7FFu], 1u);
    }
    if (blockIdx.x == 0 && (int)threadIdx.x < (n & 3)) {
        u32 a = absbits(in[n4 * 4 + threadIdx.x]);
        if ((a >> 19) == p1) atomicAdd(&h[(a >> 8) & 0x7FFu], 1u);
    }
    __syncthreads();
    u32* g = ws + H2_OFF + m * H2_BINS;
    for (int i = threadIdx.x; i < H2_BINS; i += blockDim.x)
        if (h[i]) atomicAdd(&g[i], h[i]);
}

// ---------- histogram pass 3: bits [7:0] among (bits>>8)==prefix20 ----------
__global__ void k_hist3(const float* __restrict__ in0, const float* __restrict__ in1,
                        int n0, int n1, u32* __restrict__ ws) {
    __shared__ u32 h[H3_BINS];
    const int m = blockIdx.y;
    const u32* in = (const u32*)(m ? in1 : in0);
    const int n = m ? n1 : n0;
    const int n4 = n >> 2;
    const u32* sel = ws + SEL_OFF + m * SEL_WORDS;
    const u32 pre20 = (sel[0] << 11) | sel[1];
    for (int i = threadIdx.x; i < H3_BINS; i += blockDim.x) h[i] = 0;
    __syncthreads();
    const uint4* v = (const uint4*)in;
    const int stride = gridDim.x * blockDim.x;
    for (int i = blockIdx.x * blockDim.x + threadIdx.x; i < n4; i += stride) {
        uint4 x = v[i];
        u32 a;
        a = absbits(x.x); if ((a >> 8) == pre20) atomicAdd(&h[a & 0xFFu], 1u);
        a = absbits(x.y); if ((a >> 8) == pre20) atomicAdd(&h[a & 0xFFu], 1u);
        a = absbits(x.z); if ((a >> 8) == pre20) atomicAdd(&h[a & 0xFFu], 1u);
        a = absbits(x.w); if ((a >> 8) == pre20) atomicAdd(&h[a & 0xFFu], 1u);
    }
    if (blockIdx.x == 0 && (int)threadIdx.x < (n & 3)) {
        u32 a = absbits(in[n4 * 4 + threadIdx.x]);
        if ((a >> 8) == pre20) atomicAdd(&h[a & 0xFFu], 1u);
    }
    __syncthreads();
    u32* g = ws + H3_OFF + m * H3_BINS;
    for (int i = threadIdx.x; i < H3_BINS; i += blockDim.x)
        if (h[i]) atomicAdd(&g[i], h[i]);
}

// ---------- select bin (suffix-scan from top); one block per matrix ----------
__global__ void k_select(u32* __restrict__ ws, int pass, int K0, int K1) {
    __shared__ u32 sh[256];
    const int m = blockIdx.x;
    u32* sel = ws + SEL_OFF + m * SEL_WORDS;
    const u32* hist;
    int bins;
    if (pass == 0)      { hist = ws + H1_OFF + m * H1_BINS; bins = H1_BINS; }
    else if (pass == 1) { hist = ws + H2_OFF + m * H2_BINS; bins = H2_BINS; }
    else                { hist = ws + H3_OFF + m * H3_BINS; bins = H3_BINS; }
    const u32 K = (u32)(m ? K1 : K0);
    u32 Gprev = 0;
    if (pass == 1) Gprev = sel[2];
    else if (pass == 2) Gprev = sel[5];
    const u32 Krem = K - Gprev;   // #largest still needed within current prefix

    const int tid = threadIdx.x;
    const int C = bins / 256;
    const int base = tid * C;
    u32 s = 0;
    for (int i = 0; i < C; i++) s += hist[base + i];
    sh[tid] = s;
    __syncthreads();
    if (tid == 0) {               // suffix sums over 256 chunk totals
        u32 run = 0;
        for (int i = 255; i >= 0; i--) { u32 x = sh[i]; sh[i] = run; run += x; }
    }
    __syncthreads();
    u32 running = sh[tid];        // count of elements in bins above this chunk
    for (int bin = base + C - 1; bin >= base; bin--) {
        u32 c = hist[bin];
        if (running < Krem && running + c >= Krem) {  // exactly one (bin) satisfies
            if (pass == 0)      { sel[0] = (u32)bin; sel[2] = running; }
            else if (pass == 1) { sel[1] = (u32)bin; sel[5] = Gprev + running; }
            else {
                sel[3] = (sel[0] << 19) | (sel[1] << 8) | (u32)bin;  // threshold bits t
                sel[4] = Krem - running;                             // R = ones among ties
            }
        }
        running += c;
    }
}

// ---------- final mask write + collect tied indices ----------
__global__ void k_mask(const float* __restrict__ in0, const float* __restrict__ in1,
                       float* __restrict__ out0, float* __restrict__ out1,
                       int n0, int n1, u32* __restrict__ ws) {
    const int m = blockIdx.y;
    const u32* in = (const u32*)(m ? in1 : in0);
    float* out = m ? out1 : out0;
    const int n = m ? n1 : n0;
    const int n4 = n >> 2;
    u32* sel = ws + SEL_OFF + m * SEL_WORDS;
    const u32 t = sel[3];
    u32* eq = ws + EQ_OFF + m * EQ_CAP;
    const uint4* v = (const uint4*)in;
    float4* o = (float4*)out;
    const int stride = gridDim.x * blockDim.x;
    for (int i = blockIdx.x * blockDim.x + threadIdx.x; i < n4; i += stride) {
        uint4 x = v[i];
        u32 a0 = absbits(x.x), a1 = absbits(x.y), a2 = absbits(x.z), a3 = absbits(x.w);
        float4 r;
        r.x = (a0 > t) ? 1.0f : 0.0f;
        r.y = (a1 > t) ? 1.0f : 0.0f;
        r.z = (a2 > t) ? 1.0f : 0.0f;
        r.w = (a3 > t) ? 1.0f : 0.0f;
        o[i] = r;
        if (a0 == t) { u32 p = atomicAdd(&sel[6], 1u); if (p < EQ_CAP) eq[p] = (u32)(4 * i + 0); }
        if (a1 == t) { u32 p = atomicAdd(&sel[6], 1u); if (p < EQ_CAP) eq[p] = (u32)(4 * i + 1); }
        if (a2 == t) { u32 p = atomicAdd(&sel[6], 1u); if (p < EQ_CAP) eq[p] = (u32)(4 * i + 2); }
        if (a3 == t) { u32 p = atomicAdd(&sel[6], 1u); if (p < EQ_CAP) eq[p] = (u32)(4 * i + 3); }
    }
    if (blockIdx.x == 0 && (int)threadIdx.x < (n & 3)) {
        int idx = n4 * 4 + threadIdx.x;
        u32 a = absbits(in[idx]);
        out[idx] = (a > t) ? 1.0f : 0.0f;
        if (a == t) { u32 p = atomicAdd(&sel[6], 1u); if (p < EQ_CAP) eq[p] = (u32)idx; }
    }
}

// ---------- tie resolution: stable ascending argsort keeps later indices on top ----------
__global__ void k_tie(float* __restrict__ out0, float* __restrict__ out1, u32* __restrict__ ws) {
    const int m = blockIdx.x;
    float* out = m ? out1 : out0;
    u32* sel = ws + SEL_OFF + m * SEL_WORDS;
    u32 E = sel[6]; if (E > EQ_CAP) E = EQ_CAP;
    const u32 R = sel[4];
    const u32* eq = ws + EQ_OFF + m * EQ_CAP;
    for (u32 e = threadIdx.x; e < E; e += blockDim.x) {
        u32 idx = eq[e];
        u32 cnt = 0;
        for (u32 e2 = 0; e2 < E; e2++) cnt += (eq[e2] > idx) ? 1u : 0u;
        if (cnt < R) out[idx] = 1.0f;   // the R tied elements with largest indices get 1
    }
}

extern "C" void kernel_launch(void* const* d_in, const int* in_sizes, int n_in,
                              void* d_out, int out_size, void* d_ws, size_t ws_size,
                              hipStream_t stream) {
    const float* in0 = (const float*)d_in[0];
    const float* in1 = (const float*)d_in[1];
    const int n0 = in_sizes[0];
    const int n1 = in_sizes[1];
    float* out0 = (float*)d_out;
    float* out1 = out0 + n0;
    u32* ws = (u32*)d_ws;

    // Faithful to int((1.0 - k) * n) in double precision: j = 15,099,494 for n = 16,777,216
    const double k = 0.1;
    const int j0 = (int)((1.0 - k) * (double)n0);
    const int j1 = (int)((1.0 - k) * (double)n1);
    const int K0 = n0 - j0;   // number of ones = 1,677,722
    const int K1 = n1 - j1;

    hipMemsetAsync(ws, 0, ZERO_WORDS * sizeof(u32), stream);

    dim3 hgrid(1024, 2);
    k_hist1<<<hgrid, 256, 0, stream>>>(in0, in1, n0, n1, ws);
    k_select<<<2, 256, 0, stream>>>(ws, 0, K0, K1);
    k_hist2<<<hgrid, 256, 0, stream>>>(in0, in1, n0, n1, ws);
    k_select<<<2, 256, 0, stream>>>(ws, 1, K0, K1);
    k_hist3<<<hgrid, 256, 0, stream>>>(in0, in1, n0, n1, ws);
    k_select<<<2, 256, 0, stream>>>(ws, 2, K0, K1);
    k_mask<<<dim3(1024, 2), 256, 0, stream>>>(in0, in1, out0, out1, n0, n1, ws);
    k_tie<<<2, 256, 0, stream>>>(out0, out1, ws);
}